// Round 1
// baseline (102.837 us; speedup 1.0000x reference)
//
#include <hip/hip_runtime.h>
#include <hip/hip_bf16.h>

#define NSTATES 8
#define HD      1024
#define NBATCH  16384

// output layout (flat fp32, return order)
#define OUT_MEAS 0
#define OUT_CP   16777216
#define OUT_ENT  16777224
#define OUT_COH  16777225
#define OUT_AD   16777226
#define OUT_PH   16785418

typedef __attribute__((ext_vector_type(8))) short short8;
typedef __attribute__((ext_vector_type(4))) float f32x4;

__device__ __forceinline__ short f2bf(float f) {
    union { float f; unsigned u; } x; x.f = f;
    unsigned r = x.u + 0x7fffu + ((x.u >> 16) & 1u);  // RNE
    return (short)(r >> 16);
}

// block-wide sum; valid result on thread 0 only. red = shared float[16].
__device__ __forceinline__ float blockReduceTo0(float v, float* red) {
    #pragma unroll
    for (int o = 32; o > 0; o >>= 1) v += __shfl_down(v, o, 64);
    int lane = threadIdx.x & 63, wid = threadIdx.x >> 6;
    __syncthreads();                 // protect red[] from previous use
    if (lane == 0) red[wid] = v;
    __syncthreads();
    float r = 0.f;
    if (wid == 0) {
        r = (lane < 16) ? red[lane] : 0.f;
        #pragma unroll
        for (int o = 8; o > 0; o >>= 1) r += __shfl_down(r, o, 64);
    }
    return r;
}

// ---------------- K1: amplitude pipeline (1 block, 1024 threads) ----------------
__global__ __launch_bounds__(1024) void k_amps(const float* __restrict__ AR,
                                               const float* __restrict__ AI,
                                               const float* __restrict__ H,
                                               float* __restrict__ out,
                                               float* __restrict__ w) {
    __shared__ float red[16];
    __shared__ float norms[NSTATES];
    __shared__ float Ur[NSTATES][NSTATES], Ui[NSTATES][NSTATES];

    const int d = threadIdx.x;  // hidden index
    float arv[NSTATES], aiv[NSTATES];
    #pragma unroll
    for (int s = 0; s < NSTATES; s++) {
        arv[s] = AR[s * HD + d];
        aiv[s] = AI[s * HD + d];
    }
    // per-state norms
    #pragma unroll
    for (int s = 0; s < NSTATES; s++) {
        float r = blockReduceTo0(arv[s] * arv[s] + aiv[s] * aiv[s], red);
        if (threadIdx.x == 0) norms[s] = r;
    }
    // U = expm(-i*dt*A), A = 0.5*(H+H^T). ||A||~1e-4 -> 3-term Taylor exact in fp32.
    if (threadIdx.x == 0) {
        float A[8][8], A2[8][8], A3[8][8];
        for (int i = 0; i < 8; i++)
            for (int j = 0; j < 8; j++)
                A[i][j] = 0.5f * (H[i * 8 + j] + H[j * 8 + i]) * 0.01f;  // DT/PLANCK
        for (int i = 0; i < 8; i++)
            for (int j = 0; j < 8; j++) {
                float acc = 0.f;
                for (int k = 0; k < 8; k++) acc += A[i][k] * A[k][j];
                A2[i][j] = acc;
            }
        for (int i = 0; i < 8; i++)
            for (int j = 0; j < 8; j++) {
                float acc = 0.f;
                for (int k = 0; k < 8; k++) acc += A2[i][k] * A[k][j];
                A3[i][j] = acc;
            }
        for (int i = 0; i < 8; i++)
            for (int j = 0; j < 8; j++) {
                Ur[i][j] = ((i == j) ? 1.f : 0.f) - 0.5f * A2[i][j];       // cos(A)
                Ui[i][j] = -(A[i][j] - A3[i][j] * (1.f / 6.f));            // -sin(A)
            }
    }
    __syncthreads();

    // normalize
    #pragma unroll
    for (int s = 0; s < NSTATES; s++) {
        float inv = 1.0f / sqrtf(norms[s] + 1e-8f);
        arv[s] *= inv;
        aiv[s] *= inv;
    }
    // evolve: amps = U @ amps
    float nr[NSTATES], ni[NSTATES];
    #pragma unroll
    for (int s = 0; s < NSTATES; s++) {
        float xr = 0.f, xi = 0.f;
        #pragma unroll
        for (int t = 0; t < NSTATES; t++) {
            float ur = Ur[s][t], ui = Ui[s][t];
            xr += ur * arv[t] - ui * aiv[t];
            xi += ur * aiv[t] + ui * arv[t];
        }
        nr[s] = xr; ni[s] = xi;
    }
    float dist[NSTATES], csum = 0.f, sabs = 0.f;
    #pragma unroll
    for (int s = 0; s < NSTATES; s++) {
        dist[s] = nr[s] * nr[s] + ni[s] * ni[s];
        csum += dist[s];
        sabs += sqrtf(dist[s]);
    }
    #pragma unroll
    for (int s = 0; s < NSTATES; s++) {
        out[OUT_AD + s * HD + d] = dist[s];
        out[OUT_PH + s * HD + d] = atan2f(ni[s], nr[s]);
        w[s * HD + d] = nr[s];
    }
    // collapse probs: normalize over states per d, mean over d
    float cinv = 1.0f / (csum + 1e-8f);
    #pragma unroll
    for (int s = 0; s < NSTATES; s++) {
        float r = blockReduceTo0(dist[s] * cinv, red);
        if (threadIdx.x == 0) out[OUT_CP + s] = r * (1.0f / HD);
    }
    float lam = blockReduceTo0(csum, red);
    float sa  = blockReduceTo0(sabs, red);
    if (threadIdx.x == 0) {
        out[OUT_ENT] = -(lam * logf(lam + 1e-12f));
        out[OUT_COH] = sa * sa - lam;
    }
}

// ---------------- K2: M[d,e] = sum_s w[s,e] * P[s,d,e]  (coalesced in e) --------
__global__ __launch_bounds__(256) void k_project(const float* __restrict__ P,
                                                 const float* __restrict__ w,
                                                 float* __restrict__ M) {
    int idx = blockIdx.x * 256 + threadIdx.x;   // idx = d*1024 + e
    int e = idx & (HD - 1);
    float acc = 0.f;
    #pragma unroll
    for (int s = 0; s < NSTATES; s++)
        acc += w[s * HD + e] * P[(size_t)s * HD * HD + idx];
    M[idx] = acc;
}

// ---------------- K3: Mt[e,d] = bf16(M[d,e])  (64x64 LDS tile transpose) --------
__global__ __launch_bounds__(256) void k_transpose(const float* __restrict__ M,
                                                   short* __restrict__ Mt) {
    __shared__ float tile[64][65];
    int d0 = (blockIdx.x >> 4) * 64;
    int e0 = (blockIdx.x & 15) * 64;
    int tx = threadIdx.x & 63, ty = threadIdx.x >> 6;
    #pragma unroll
    for (int j = 0; j < 16; j++) {
        int r = ty + 4 * j;
        tile[r][tx] = M[(size_t)(d0 + r) * HD + e0 + tx];
    }
    __syncthreads();
    #pragma unroll
    for (int j = 0; j < 16; j++) {
        int er = ty + 4 * j;
        Mt[(size_t)(e0 + er) * HD + d0 + tx] = f2bf(tile[tx][er]);
    }
}

// ---------------- K4: out = X @ M   (bf16 MFMA, 128x128 tile, BK=64) ------------
// 256 threads = 4 waves (2x2), each wave 64x64 = 4x4 fragments of 16x16x32.
__global__ __launch_bounds__(256) void k_gemm(const float* __restrict__ X,
                                              const short* __restrict__ Mt,
                                              float* __restrict__ out) {
    // XCD-aware swizzle (1024 blocks, %8==0 -> simple form is bijective)
    int bid = blockIdx.x;
    int swz = (bid & 7) * (1024 >> 3) + (bid >> 3);
    int bm = swz >> 3, bn = swz & 7;
    int brow = bm * 128, bcol = bn * 128;

    __shared__ short As[128 * 64];  // [row][k], XOR-swizzled in 16B chunks
    __shared__ short Bs[128 * 64];  // [n][k] (B^T), same swizzle

    int tid = threadIdx.x;
    int lane = tid & 63, wid = tid >> 6;
    int wr = wid >> 1, wc = wid & 1;

    f32x4 acc[4][4];
    #pragma unroll
    for (int m = 0; m < 4; m++)
        #pragma unroll
        for (int n = 0; n < 4; n++) acc[m][n] = (f32x4){0.f, 0.f, 0.f, 0.f};

    for (int kt = 0; kt < HD; kt += 64) {
        __syncthreads();
        // stage A: convert fp32 x -> bf16 (1024 chunks of 8 elems)
        #pragma unroll
        for (int i = 0; i < 4; i++) {
            int chunk = tid + 256 * i;
            int row = chunk >> 3, c8 = chunk & 7;
            const float* src = X + (size_t)(brow + row) * HD + kt + c8 * 8;
            float4 f0 = *reinterpret_cast<const float4*>(src);
            float4 f1 = *reinterpret_cast<const float4*>(src + 4);
            short8 v;
            v[0] = f2bf(f0.x); v[1] = f2bf(f0.y); v[2] = f2bf(f0.z); v[3] = f2bf(f0.w);
            v[4] = f2bf(f1.x); v[5] = f2bf(f1.y); v[6] = f2bf(f1.z); v[7] = f2bf(f1.w);
            *reinterpret_cast<short8*>(&As[row * 64 + ((c8 ^ (row & 7)) * 8)]) = v;
        }
        // stage B (Mt is already [n][k] bf16)
        #pragma unroll
        for (int i = 0; i < 4; i++) {
            int chunk = tid + 256 * i;
            int row = chunk >> 3, c8 = chunk & 7;
            short8 v = *reinterpret_cast<const short8*>(Mt + (size_t)(bcol + row) * HD + kt + c8 * 8);
            *reinterpret_cast<short8*>(&Bs[row * 64 + ((c8 ^ (row & 7)) * 8)]) = v;
        }
        __syncthreads();
        // compute: 2 k-sub-steps of 32
        #pragma unroll
        for (int kk = 0; kk < 2; kk++) {
            int kg = (lane >> 4) + kk * 4;  // 16B-chunk index along k
            short8 af[4], bfr[4];
            #pragma unroll
            for (int m = 0; m < 4; m++) {
                int row = wr * 64 + m * 16 + (lane & 15);
                af[m] = *reinterpret_cast<short8*>(&As[row * 64 + ((kg ^ (row & 7)) * 8)]);
            }
            #pragma unroll
            for (int n = 0; n < 4; n++) {
                int row = wc * 64 + n * 16 + (lane & 15);
                bfr[n] = *reinterpret_cast<short8*>(&Bs[row * 64 + ((kg ^ (row & 7)) * 8)]);
            }
            #pragma unroll
            for (int m = 0; m < 4; m++)
                #pragma unroll
                for (int n = 0; n < 4; n++)
                    acc[m][n] = __builtin_amdgcn_mfma_f32_16x16x32_bf16(af[m], bfr[n], acc[m][n], 0, 0, 0);
        }
    }
    // epilogue: C/D layout col=lane&15, row=(lane>>4)*4+j  [m89-verified]
    #pragma unroll
    for (int m = 0; m < 4; m++)
        #pragma unroll
        for (int n = 0; n < 4; n++)
            #pragma unroll
            for (int j = 0; j < 4; j++) {
                int r = brow + wr * 64 + m * 16 + (lane >> 4) * 4 + j;
                int c = bcol + wc * 64 + n * 16 + (lane & 15);
                out[(size_t)r * HD + c] = acc[m][n][j];
            }
}

extern "C" void kernel_launch(void* const* d_in, const int* in_sizes, int n_in,
                              void* d_out, int out_size, void* d_ws, size_t ws_size,
                              hipStream_t stream) {
    const float* X  = (const float*)d_in[0];  // [16384,1024]
    const float* AR = (const float*)d_in[1];  // [8,1024]
    const float* AI = (const float*)d_in[2];  // [8,1024]
    const float* H  = (const float*)d_in[3];  // [8,8]
    const float* P  = (const float*)d_in[4];  // [8,1024,1024]
    float* out = (float*)d_out;

    char* ws = (char*)d_ws;
    float* w  = (float*)ws;                       // 8*1024 fp32   (32 KB)
    float* M  = (float*)(ws + 32768);             // 1024*1024 fp32 (4 MB)
    short* Mt = (short*)(ws + 32768 + 4194304);   // 1024*1024 bf16 (2 MB)

    k_amps<<<1, 1024, 0, stream>>>(AR, AI, H, out, w);
    k_project<<<(HD * HD) / 256, 256, 0, stream>>>(P, w, M);
    k_transpose<<<256, 256, 0, stream>>>(M, Mt);
    k_gemm<<<(NBATCH / 128) * (HD / 128), 256, 0, stream>>>(X, Mt, out);
}